// Round 4
// baseline (823.262 us; speedup 1.0000x reference)
//
#include <hip/hip_runtime.h>
#include <math.h>

#define BGR 256        // graphs
#define NPG0 400       // nodes per graph (initial)
#define NN (BGR*NPG0)  // 102400 nodes
#define NE (NN*16)     // 1638400 edges
#define HD 128
#define CAP 64         // max in-degree capacity

typedef __attribute__((ext_vector_type(8))) short short8;
typedef __attribute__((ext_vector_type(4))) float floatx4;

__device__ __forceinline__ unsigned short f2b(float f) {
    unsigned int u = __builtin_bit_cast(unsigned int, f);
    unsigned int r = (u + 0x7fffu + ((u >> 16) & 1u)) >> 16;
    return (unsigned short)r;
}
__device__ __forceinline__ float b2f(unsigned short h) {
    return __builtin_bit_cast(float, (unsigned int)h << 16);
}
__device__ __forceinline__ float b2f_lo(unsigned int u) {
    return __builtin_bit_cast(float, u << 16);
}
__device__ __forceinline__ float b2f_hi(unsigned int u) {
    return __builtin_bit_cast(float, u & 0xffff0000u);
}
__device__ __forceinline__ void acc8(float* a, uint4 u) {
    a[0] += b2f_lo(u.x); a[1] += b2f_hi(u.x);
    a[2] += b2f_lo(u.y); a[3] += b2f_hi(u.y);
    a[4] += b2f_lo(u.z); a[5] += b2f_hi(u.z);
    a[6] += b2f_lo(u.w); a[7] += b2f_hi(u.w);
}

// ---------------- CSR build (fixed capacity, by dst) ----------------
__global__ void k_build(const int* __restrict__ src, const int* __restrict__ dst,
                        int* __restrict__ cnt, int* __restrict__ col) {
    int e = blockIdx.x * 256 + threadIdx.x;
    if (e >= NE) return;
    int d = dst[e];
    int s = src[e];
    int i = atomicAdd(&cnt[d], 1);
    if (i < CAP) col[d * CAP + i] = s;
}

__global__ void k_init_alive(float* __restrict__ alive) {
    int i = blockIdx.x * 256 + threadIdx.x;
    if (i < NN) alive[i] = 1.0f;
}

// rliv[o] = 1 / max(sum_j alive[src_j], 1)
__global__ void k_rliv(const int* __restrict__ cnt, const int* __restrict__ col,
                       const float* __restrict__ alive, float* __restrict__ rliv) {
    int o = blockIdx.x * 256 + threadIdx.x;
    if (o >= NN) return;
    int n = cnt[o]; if (n > CAP) n = CAP;
    const int* c = &col[(long)o * CAP];
    float s = 0.0f;
    for (int i = 0; i < n; i++) s += alive[c[i]];
    rliv[o] = 1.0f / fmaxf(s, 1.0f);
}

// ---------------- W -> bf16, transposed: bt[m][n*128 + k] = bf16(W_m[k*128 + n])
__global__ void k_wcvt(const float* __restrict__ c1_wr, const float* __restrict__ c1_ws,
                       const float* __restrict__ cs_wr, const float* __restrict__ cs_ws,
                       unsigned short* __restrict__ bt) {
    int m = blockIdx.y;
    int idx = blockIdx.x * 256 + threadIdx.x;       // 0..16383
    const float* W = (m == 0) ? c1_wr : (m == 1) ? c1_ws
                   : (m < 6) ? (cs_wr + (m - 2) * HD * HD) : (cs_ws + (m - 6) * HD * HD);
    int n = idx >> 7, k = idx & 127;
    bt[m * HD * HD + idx] = f2b(W[k * HD + n]);
}

// ---------------- graph-resident mean aggregation
// block = (graph g, feature-half h): stage 400 rows x 64 feats bf16 into LDS,
// then gather neighbor rows from LDS. Grid 512, 2 blocks/CU.
template<bool XF32>
__global__ __launch_bounds__(256) void k_agg_g(const void* __restrict__ x_v,
    const int* __restrict__ cnt, const int* __restrict__ col,
    const float* __restrict__ alive, const float* __restrict__ rliv,
    unsigned short* __restrict__ mean)
{
    __shared__ unsigned short sS[NPG0 * 72];   // stride 72 shorts (144B, 16B-aligned, bank-skewed)
    int b = blockIdx.x;
    int g = b >> 1, half = b & 1;
    int t = threadIdx.x;
    long gbase = (long)g * NPG0;

    if (XF32) {
        const float4* xf = (const float4*)x_v;
        for (int flat = t; flat < NPG0 * 8; flat += 256) {
            int r = flat >> 3, u8 = flat & 7;
            long fi = (gbase + r) * 32 + half * 16 + u8 * 2;
            float4 v0 = xf[fi], v1 = xf[fi + 1];
            uint4 wv;
            wv.x = (unsigned)f2b(v0.x) | ((unsigned)f2b(v0.y) << 16);
            wv.y = (unsigned)f2b(v0.z) | ((unsigned)f2b(v0.w) << 16);
            wv.z = (unsigned)f2b(v1.x) | ((unsigned)f2b(v1.y) << 16);
            wv.w = (unsigned)f2b(v1.z) | ((unsigned)f2b(v1.w) << 16);
            *(uint4*)&sS[r * 72 + u8 * 8] = wv;
        }
    } else {
        const uint4* xb = (const uint4*)x_v;
        for (int flat = t; flat < NPG0 * 8; flat += 256) {
            int r = flat >> 3, u8 = flat & 7;
            *(uint4*)&sS[r * 72 + u8 * 8] = xb[(gbase + r) * 16 + half * 8 + u8];
        }
    }
    __syncthreads();

    int lane = t & 63, wv = t >> 6;          // 4 waves
    int sub = lane >> 3, fl = lane & 7;      // 8 nodes/wave, 8 feat-octets/node
    for (int step = 0; step < 13; ++step) {
        int ol = step * 32 + wv * 8 + sub;
        if (ol < NPG0) {
            long o = gbase + ol;
            if (alive[o] != 0.0f) {
                int n = cnt[o]; if (n > CAP) n = CAP;
                const int* cp = &col[o * (long)CAP];
                float acc[8] = {0, 0, 0, 0, 0, 0, 0, 0};
                int i = 0;
                for (; i + 4 <= n; i += 4) {
                    int s0 = cp[i] - (int)gbase;
                    int s1 = cp[i + 1] - (int)gbase;
                    int s2 = cp[i + 2] - (int)gbase;
                    int s3 = cp[i + 3] - (int)gbase;
                    uint4 u0 = *(const uint4*)&sS[s0 * 72 + fl * 8];
                    uint4 u1 = *(const uint4*)&sS[s1 * 72 + fl * 8];
                    uint4 u2 = *(const uint4*)&sS[s2 * 72 + fl * 8];
                    uint4 u3 = *(const uint4*)&sS[s3 * 72 + fl * 8];
                    acc8(acc, u0); acc8(acc, u1); acc8(acc, u2); acc8(acc, u3);
                }
                for (; i < n; i++) {
                    uint4 u0 = *(const uint4*)&sS[(cp[i] - (int)gbase) * 72 + fl * 8];
                    acc8(acc, u0);
                }
                float rl = rliv[o];
                uint4 wo;
                wo.x = (unsigned)f2b(acc[0] * rl) | ((unsigned)f2b(acc[1] * rl) << 16);
                wo.y = (unsigned)f2b(acc[2] * rl) | ((unsigned)f2b(acc[3] * rl) << 16);
                wo.z = (unsigned)f2b(acc[4] * rl) | ((unsigned)f2b(acc[5] * rl) << 16);
                wo.w = (unsigned)f2b(acc[6] * rl) | ((unsigned)f2b(acc[7] * rl) << 16);
                *(uint4*)&mean[o * HD + half * 64 + fl * 8] = wo;
            }
        }
    }
}

// ---------------- MFMA conv: xout = relu(mean@Wr + x@Ws + b), 64 nodes x 128 cols / block
// both A-tiles staged before ONE barrier; B-frags streamed per-ks from L2-hot weights
template<bool XF32>
__global__ __launch_bounds__(256) void k_conv_mfma(
    const void* __restrict__ xin_v, unsigned short* __restrict__ xout,
    const unsigned short* __restrict__ meanb, const float* __restrict__ alive,
    const unsigned short* __restrict__ wr_bt, const unsigned short* __restrict__ ws_bt,
    const float* __restrict__ bias, float* __restrict__ hcat, int layer)
{
    __shared__ unsigned short sM[64 * 136];
    __shared__ unsigned short sX[64 * 136];
    __shared__ float sAl[64];
    int t = threadIdx.x;
    int base = blockIdx.x * 64;
    if (t < 64) sAl[t] = alive[base + t];

    {
        const uint4* mp = (const uint4*)meanb;
        for (int flat = t; flat < 64 * 16; flat += 256) {
            int r = flat >> 4, u8 = flat & 15;
            *(uint4*)&sM[r * 136 + u8 * 8] = mp[(long)(base + r) * 16 + u8];
        }
    }
    if (XF32) {
        const float4* xf = (const float4*)xin_v;
        for (int flat = t; flat < 64 * 16; flat += 256) {
            int r = flat >> 4, u8 = flat & 15;
            long fi = (long)(base + r) * 32 + u8 * 2;
            float4 v0 = xf[fi], v1 = xf[fi + 1];
            uint4 wv;
            wv.x = (unsigned)f2b(v0.x) | ((unsigned)f2b(v0.y) << 16);
            wv.y = (unsigned)f2b(v0.z) | ((unsigned)f2b(v0.w) << 16);
            wv.z = (unsigned)f2b(v1.x) | ((unsigned)f2b(v1.y) << 16);
            wv.w = (unsigned)f2b(v1.z) | ((unsigned)f2b(v1.w) << 16);
            *(uint4*)&sX[r * 136 + u8 * 8] = wv;
        }
    } else {
        const uint4* xb = (const uint4*)xin_v;
        for (int flat = t; flat < 64 * 16; flat += 256) {
            int r = flat >> 4, u8 = flat & 15;
            *(uint4*)&sX[r * 136 + u8 * 8] = xb[(long)(base + r) * 16 + u8];
        }
    }

    int lane = t & 63, wid = t >> 6;
    int quad = lane >> 4, l15 = lane & 15;
    int wrow0 = (wid & 1) * 32, wcol0 = (wid >> 1) * 64;
    floatx4 acc[2][4];
#pragma unroll
    for (int ct = 0; ct < 4; ++ct) {
        float b = bias[wcol0 + ct * 16 + l15];
#pragma unroll
        for (int nt = 0; nt < 2; ++nt) { acc[nt][ct][0] = b; acc[nt][ct][1] = b; acc[nt][ct][2] = b; acc[nt][ct][3] = b; }
    }
    __syncthreads();

#pragma unroll
    for (int ks = 0; ks < 4; ++ks) {
        short8 Bv[4];
#pragma unroll
        for (int ct = 0; ct < 4; ++ct)
            Bv[ct] = *(const short8*)&wr_bt[(wcol0 + ct * 16 + l15) * HD + ks * 32 + quad * 8];
        short8 Af[2];
#pragma unroll
        for (int nt = 0; nt < 2; ++nt)
            Af[nt] = *(const short8*)&sM[(wrow0 + nt * 16 + l15) * 136 + ks * 32 + quad * 8];
#pragma unroll
        for (int ct = 0; ct < 4; ++ct)
#pragma unroll
            for (int nt = 0; nt < 2; ++nt)
                acc[nt][ct] = __builtin_amdgcn_mfma_f32_16x16x32_bf16(Af[nt], Bv[ct], acc[nt][ct], 0, 0, 0);
    }
#pragma unroll
    for (int ks = 0; ks < 4; ++ks) {
        short8 Bv[4];
#pragma unroll
        for (int ct = 0; ct < 4; ++ct)
            Bv[ct] = *(const short8*)&ws_bt[(wcol0 + ct * 16 + l15) * HD + ks * 32 + quad * 8];
        short8 Af[2];
#pragma unroll
        for (int nt = 0; nt < 2; ++nt)
            Af[nt] = *(const short8*)&sX[(wrow0 + nt * 16 + l15) * 136 + ks * 32 + quad * 8];
#pragma unroll
        for (int ct = 0; ct < 4; ++ct)
#pragma unroll
            for (int nt = 0; nt < 2; ++nt)
                acc[nt][ct] = __builtin_amdgcn_mfma_f32_16x16x32_bf16(Af[nt], Bv[ct], acc[nt][ct], 0, 0, 0);
    }

    // epilogue: relu, alive-gate, bf16 store, per-graph readout
    int g0 = base / NPG0;
    int cut = (g0 + 1) * NPG0 - base;     // rows >= cut belong to g0+1
    bool hasB = cut < 64;
#pragma unroll
    for (int ct = 0; ct < 4; ++ct) {
        int j = wcol0 + ct * 16 + l15;
        float ps0 = 0.0f, ps1 = 0.0f;
#pragma unroll
        for (int nt = 0; nt < 2; ++nt) {
#pragma unroll
            for (int rr = 0; rr < 4; ++rr) {
                int row = wrow0 + nt * 16 + quad * 4 + rr;
                float v = fmaxf(acc[nt][ct][rr], 0.0f);
                if (sAl[row] != 0.0f) {
                    xout[(long)(base + row) * HD + j] = f2b(v);
                    if (row < cut) ps0 += v; else ps1 += v;
                }
            }
        }
        ps0 += __shfl_xor(ps0, 16); ps0 += __shfl_xor(ps0, 32);
        if (hasB) { ps1 += __shfl_xor(ps1, 16); ps1 += __shfl_xor(ps1, 32); }
        if (quad == 0) {
            atomicAdd(&hcat[g0 * (5 * HD) + layer * HD + j], ps0);
            if (hasB) atomicAdd(&hcat[(g0 + 1) * (5 * HD) + layer * HD + j], ps1);
        }
    }
}

// ---------------- pool scores (x is bf16): tr = x.wr ; tsb = x.ws + b
__global__ __launch_bounds__(256) void k_dots(const unsigned short* __restrict__ x,
    const float* __restrict__ wr, const float* __restrict__ ws, const float* __restrict__ pb,
    float* __restrict__ tr, float* __restrict__ tsb) {
    int lane = threadIdx.x;                    // 0..31
    int o = blockIdx.x * 8 + threadIdx.y;
    uint2 u = ((const uint2*)x)[(long)o * 32 + lane];
    float x0 = b2f_lo(u.x), x1 = b2f_hi(u.x), x2 = b2f_lo(u.y), x3 = b2f_hi(u.y);
    float4 w1 = ((const float4*)wr)[lane];
    float4 w2 = ((const float4*)ws)[lane];
    float a = x0 * w1.x + x1 * w1.y + x2 * w1.z + x3 * w1.w;
    float c = x0 * w2.x + x1 * w2.y + x2 * w2.z + x3 * w2.w;
#pragma unroll
    for (int m = 1; m < 32; m <<= 1) {
        a += __shfl_xor(a, m);
        c += __shfl_xor(c, m);
    }
    if (lane == 0) { tr[o] = a; tsb[o] = c + pb[0]; }
}

__global__ __launch_bounds__(256) void k_score2(const int* __restrict__ cnt, const int* __restrict__ col,
    const float* __restrict__ alive, const float* __restrict__ rliv,
    const float* __restrict__ tr, const float* __restrict__ tsb,
    float* __restrict__ score) {
    int o = blockIdx.x * 256 + threadIdx.x;
    if (o >= NN) return;
    if (alive[o] == 0.0f) { score[o] = -INFINITY; return; }
    int n = cnt[o]; if (n > CAP) n = CAP;
    const int* c = &col[(long)o * CAP];
    float s = 0.0f;
    for (int i = 0; i < n; i++) s += tr[c[i]];
    score[o] = s * rliv[o] + tsb[o];
}

// ---------------- per-graph top-K (ties: lowest index), scale kept x by tanh(score), zero dropped
__global__ __launch_bounds__(256) void k_topk(unsigned short* __restrict__ x, float* __restrict__ alive,
                        const float* __restrict__ score, int K) {
    __shared__ float s[512];
    __shared__ float sc[NPG0];
    __shared__ float mult[NPG0];
    __shared__ unsigned char keep[NPG0];
    __shared__ int cnt_gt;
    int g = blockIdx.x, t = threadIdx.x;
    long nb = (long)g * NPG0;
    for (int i = t; i < 512; i += 256) {
        float v = (i < NPG0) ? score[nb + i] : -INFINITY;
        s[i] = v;
        if (i < NPG0) sc[i] = v;
    }
    if (t == 0) cnt_gt = 0;
    __syncthreads();
    for (int ksz = 2; ksz <= 512; ksz <<= 1) {
        for (int jsz = ksz >> 1; jsz >= 1; jsz >>= 1) {
            for (int i = t; i < 512; i += 256) {
                int ixj = i ^ jsz;
                if (ixj > i) {
                    float a = s[i], c = s[ixj];
                    bool up = ((i & ksz) == 0);
                    if ((a > c) == up) { s[i] = c; s[ixj] = a; }
                }
            }
            __syncthreads();
        }
    }
    float thr = s[512 - K];
    for (int n = t; n < NPG0; n += 256)
        if (sc[n] > thr) atomicAdd(&cnt_gt, 1);
    __syncthreads();
    if (t == 0) {
        int m = K - cnt_gt, tk = 0;
        for (int n = 0; n < NPG0; n++) {
            bool kp = sc[n] > thr;
            if (!kp && sc[n] == thr && tk < m) { kp = true; tk++; }
            keep[n] = kp ? 1 : 0;
        }
    }
    __syncthreads();
    for (int n = t; n < NPG0; n += 256) {
        mult[n] = keep[n] ? tanhf(sc[n]) : 0.0f;
        alive[nb + n] = keep[n] ? 1.0f : 0.0f;
    }
    __syncthreads();
    for (int idx = t; idx < NPG0 * HD / 4; idx += 256) {
        int n = idx >> 5, c4 = idx & 31;
        uint2* p = (uint2*)&x[(nb + n) * HD + c4 * 4];
        uint2 u = *p;
        float m = mult[n];
        uint2 w;
        w.x = (unsigned)f2b(b2f_lo(u.x) * m) | ((unsigned)f2b(b2f_hi(u.x) * m) << 16);
        w.y = (unsigned)f2b(b2f_lo(u.y) * m) | ((unsigned)f2b(b2f_hi(u.y) * m) << 16);
        *p = w;
    }
}

// ---------------- final MLP + log_softmax (hcat holds SUMS; divide by npg here)
__global__ __launch_bounds__(128) void k_mlp(const float* __restrict__ h, const float* __restrict__ w1,
    const float* __restrict__ b1, const float* __restrict__ w2,
    const float* __restrict__ b2, float* __restrict__ out) {
    __shared__ float h1[HD];
    __shared__ float red[HD];
    __shared__ float lg[2];
    const float inv[5] = {1.0f/400.0f, 1.0f/400.0f, 1.0f/320.0f, 1.0f/320.0f, 1.0f/256.0f};
    int g = blockIdx.x, j = threadIdx.x;
    const float* hg = &h[g * (5 * HD)];
    float acc = b1[j];
    for (int k = 0; k < 5 * HD; k++) acc += hg[k] * inv[k >> 7] * w1[k * HD + j];
    h1[j] = fmaxf(acc, 0.0f);
    __syncthreads();
    for (int c = 0; c < 2; c++) {
        red[j] = h1[j] * w2[j * 2 + c];
        __syncthreads();
        for (int st = 64; st > 0; st >>= 1) {
            if (j < st) red[j] += red[j + st];
            __syncthreads();
        }
        if (j == 0) lg[c] = red[0] + b2[c];
        __syncthreads();
    }
    if (j == 0) {
        float l0 = lg[0], l1 = lg[1];
        float m = fmaxf(l0, l1);
        float lse = m + logf(expf(l0 - m) + expf(l1 - m));
        out[g * 2 + 0] = l0 - lse;
        out[g * 2 + 1] = l1 - lse;
    }
}

extern "C" void kernel_launch(void* const* d_in, const int* in_sizes, int n_in,
                              void* d_out, int out_size, void* d_ws, size_t ws_size,
                              hipStream_t stream) {
    const float* x_in   = (const float*)d_in[0];
    const int*   eidx   = (const int*)d_in[1];
    const int*   e_src  = eidx;
    const int*   e_dst  = eidx + NE;
    const float* c1_wr  = (const float*)d_in[3];
    const float* c1_ws  = (const float*)d_in[4];
    const float* c1_b   = (const float*)d_in[5];
    const float* cs_wr  = (const float*)d_in[6];
    const float* cs_ws  = (const float*)d_in[7];
    const float* cs_b   = (const float*)d_in[8];
    const float* p_wr   = (const float*)d_in[9];
    const float* p_ws   = (const float*)d_in[10];
    const float* p_b    = (const float*)d_in[11];
    const float* l1_w   = (const float*)d_in[12];
    const float* l1_b   = (const float*)d_in[13];
    const float* l2_w   = (const float*)d_in[14];
    const float* l2_b   = (const float*)d_in[15];
    float* out = (float*)d_out;

    char* ws = (char*)d_ws;
    size_t off = 0;
    int*   cnt   = (int*)(ws + off);             off += (size_t)NN * 4;
    int*   col   = (int*)(ws + off);             off += (size_t)NN * CAP * 4;
    float* alive = (float*)(ws + off);           off += (size_t)NN * 4;
    float* rliv  = (float*)(ws + off);           off += (size_t)NN * 4;
    unsigned short* xbuf  = (unsigned short*)(ws + off); off += (size_t)NN * HD * 2;
    unsigned short* meanb = (unsigned short*)(ws + off); off += (size_t)NN * HD * 2;
    float* score = (float*)(ws + off);           off += (size_t)NN * 4;
    float* trb   = (float*)(ws + off);           off += (size_t)NN * 4;
    float* tsb   = (float*)(ws + off);           off += (size_t)NN * 4;
    float* hcat  = (float*)(ws + off);           off += (size_t)BGR * 5 * HD * 4;
    unsigned short* wbt = (unsigned short*)(ws + off); off += (size_t)10 * HD * HD * 2;

    hipMemsetAsync(cnt, 0, (size_t)NN * 4, stream);
    hipMemsetAsync(hcat, 0, (size_t)BGR * 5 * HD * 4, stream);
    k_build<<<(NE + 255) / 256, 256, 0, stream>>>(e_src, e_dst, cnt, col);
    k_init_alive<<<(NN + 255) / 256, 256, 0, stream>>>(alive);
    k_rliv<<<NN / 256, 256, 0, stream>>>(cnt, col, alive, rliv);
    k_wcvt<<<dim3(64, 10), 256, 0, stream>>>(c1_wr, c1_ws, cs_wr, cs_ws, wbt);

    dim3 a32(32, 8);
    unsigned short* bt_wr[5] = { wbt + 0 * HD * HD, wbt + 2 * HD * HD, wbt + 3 * HD * HD, wbt + 4 * HD * HD, wbt + 5 * HD * HD };
    unsigned short* bt_ws[5] = { wbt + 1 * HD * HD, wbt + 6 * HD * HD, wbt + 7 * HD * HD, wbt + 8 * HD * HD, wbt + 9 * HD * HD };

    // conv1 (x fp32 in)
    k_agg_g<true><<<BGR * 2, 256, 0, stream>>>(x_in, cnt, col, alive, rliv, meanb);
    k_conv_mfma<true><<<NN / 64, 256, 0, stream>>>(x_in, xbuf, meanb, alive, bt_wr[0], bt_ws[0], c1_b, hcat, 0);

    // convs[0]
    k_agg_g<false><<<BGR * 2, 256, 0, stream>>>(xbuf, cnt, col, alive, rliv, meanb);
    k_conv_mfma<false><<<NN / 64, 256, 0, stream>>>(xbuf, xbuf, meanb, alive, bt_wr[1], bt_ws[1], cs_b + 0 * HD, hcat, 1);

    // pool 0 (K=320)
    k_dots<<<NN / 8, a32, 0, stream>>>(xbuf, p_wr + 0 * HD, p_ws + 0 * HD, p_b + 0, trb, tsb);
    k_score2<<<NN / 256, 256, 0, stream>>>(cnt, col, alive, rliv, trb, tsb, score);
    k_topk<<<BGR, 256, 0, stream>>>(xbuf, alive, score, 320);
    k_rliv<<<NN / 256, 256, 0, stream>>>(cnt, col, alive, rliv);

    // convs[1]
    k_agg_g<false><<<BGR * 2, 256, 0, stream>>>(xbuf, cnt, col, alive, rliv, meanb);
    k_conv_mfma<false><<<NN / 64, 256, 0, stream>>>(xbuf, xbuf, meanb, alive, bt_wr[2], bt_ws[2], cs_b + 1 * HD, hcat, 2);

    // convs[2]
    k_agg_g<false><<<BGR * 2, 256, 0, stream>>>(xbuf, cnt, col, alive, rliv, meanb);
    k_conv_mfma<false><<<NN / 64, 256, 0, stream>>>(xbuf, xbuf, meanb, alive, bt_wr[3], bt_ws[3], cs_b + 2 * HD, hcat, 3);

    // pool 1 (K=256)
    k_dots<<<NN / 8, a32, 0, stream>>>(xbuf, p_wr + 1 * HD, p_ws + 1 * HD, p_b + 1, trb, tsb);
    k_score2<<<NN / 256, 256, 0, stream>>>(cnt, col, alive, rliv, trb, tsb, score);
    k_topk<<<BGR, 256, 0, stream>>>(xbuf, alive, score, 256);
    k_rliv<<<NN / 256, 256, 0, stream>>>(cnt, col, alive, rliv);

    // convs[3]
    k_agg_g<false><<<BGR * 2, 256, 0, stream>>>(xbuf, cnt, col, alive, rliv, meanb);
    k_conv_mfma<false><<<NN / 64, 256, 0, stream>>>(xbuf, xbuf, meanb, alive, bt_wr[4], bt_ws[4], cs_b + 3 * HD, hcat, 4);

    // MLP head
    k_mlp<<<BGR, HD, 0, stream>>>(hcat, l1_w, l1_b, l2_w, l2_b, out);
}

// Round 5
// 744.768 us; speedup vs baseline: 1.1054x; 1.1054x over previous
//
#include <hip/hip_runtime.h>
#include <math.h>

#define BGR 256        // graphs
#define NPG0 400       // nodes per graph (initial)
#define NN (BGR*NPG0)  // 102400 nodes
#define NE (NN*16)     // 1638400 edges
#define HD 128
#define CAP 64         // max in-degree capacity
#define TR 64          // rows per k_layer tile (grid = NN/TR = 1600)
#define LSTR 136       // LDS row stride in shorts (68 dw, %32==4 -> conflict-free b128)

typedef __attribute__((ext_vector_type(8))) short short8;
typedef __attribute__((ext_vector_type(4))) float floatx4;

__device__ __forceinline__ unsigned short f2b(float f) {
    unsigned int u = __builtin_bit_cast(unsigned int, f);
    unsigned int r = (u + 0x7fffu + ((u >> 16) & 1u)) >> 16;
    return (unsigned short)r;
}
__device__ __forceinline__ float b2f_lo(unsigned int u) {
    return __builtin_bit_cast(float, u << 16);
}
__device__ __forceinline__ float b2f_hi(unsigned int u) {
    return __builtin_bit_cast(float, u & 0xffff0000u);
}
__device__ __forceinline__ void acc8(float* a, uint4 u) {
    a[0] += b2f_lo(u.x); a[1] += b2f_hi(u.x);
    a[2] += b2f_lo(u.y); a[3] += b2f_hi(u.y);
    a[4] += b2f_lo(u.z); a[5] += b2f_hi(u.z);
    a[6] += b2f_lo(u.w); a[7] += b2f_hi(u.w);
}
__device__ __forceinline__ void accf(float* a, float4 u, float4 v) {
    a[0] += u.x; a[1] += u.y; a[2] += u.z; a[3] += u.w;
    a[4] += v.x; a[5] += v.y; a[6] += v.z; a[7] += v.w;
}
__device__ __forceinline__ uint4 pack8(const float* a) {
    uint4 w;
    w.x = (unsigned)f2b(a[0]) | ((unsigned)f2b(a[1]) << 16);
    w.y = (unsigned)f2b(a[2]) | ((unsigned)f2b(a[3]) << 16);
    w.z = (unsigned)f2b(a[4]) | ((unsigned)f2b(a[5]) << 16);
    w.w = (unsigned)f2b(a[6]) | ((unsigned)f2b(a[7]) << 16);
    return w;
}

// ---------------- CSR build (fixed capacity, by dst) ----------------
__global__ void k_build(const int* __restrict__ src, const int* __restrict__ dst,
                        int* __restrict__ cnt, int* __restrict__ col) {
    int e = blockIdx.x * 256 + threadIdx.x;
    if (e >= NE) return;
    int d = dst[e];
    int s = src[e];
    int i = atomicAdd(&cnt[d], 1);
    if (i < CAP) col[d * CAP + i] = s;
}

// alive=1, rliv = 1/max(deg,1)   (all nodes alive initially)
__global__ void k_initrl(const int* __restrict__ cnt, float* __restrict__ alive,
                         float* __restrict__ rliv) {
    int i = blockIdx.x * 256 + threadIdx.x;
    if (i >= NN) return;
    alive[i] = 1.0f;
    int n = cnt[i]; if (n > CAP) n = CAP;
    rliv[i] = 1.0f / fmaxf((float)n, 1.0f);
}

// ---------------- W -> bf16, transposed: bt[m][n*128 + k] = bf16(W_m[k*128 + n])
__global__ void k_wcvt(const float* __restrict__ c1_wr, const float* __restrict__ c1_ws,
                       const float* __restrict__ cs_wr, const float* __restrict__ cs_ws,
                       unsigned short* __restrict__ bt) {
    int m = blockIdx.y;
    int idx = blockIdx.x * 256 + threadIdx.x;       // 0..16383
    const float* W = (m == 0) ? c1_wr : (m == 1) ? c1_ws
                   : (m < 6) ? (cs_wr + (m - 2) * HD * HD) : (cs_ws + (m - 6) * HD * HD);
    int n = idx >> 7, k = idx & 127;
    bt[m * HD * HD + idx] = f2b(W[k * HD + n]);
}

// ---------------- fused layer: mean-agg (L2 gather -> LDS) + MFMA conv + readout
// block: 64 rows x 128 cols. xin != xout (ping-pong). Dead rows written as 0.
template<bool XF32>
__global__ __launch_bounds__(256) void k_layer(
    const void* __restrict__ xin_v, unsigned short* __restrict__ xout,
    const int* __restrict__ cnt, const int* __restrict__ col,
    const float* __restrict__ alive, const float* __restrict__ rliv,
    const unsigned short* __restrict__ wr_bt, const unsigned short* __restrict__ ws_bt,
    const float* __restrict__ bias, float* __restrict__ hcat, int layer)
{
    __shared__ unsigned short sM[TR * LSTR];
    __shared__ unsigned short sX[TR * LSTR];
    __shared__ float sAl[TR];
    int t = threadIdx.x;
    int b = blockIdx.x;
    int base = ((b & 7) * 200 + (b >> 3)) * TR;   // XCD swizzle: graph slices stay in one L2

    if (t < TR) sAl[t] = alive[base + t];

    // ---- stage own x-tile -> sX (coalesced)
    if (XF32) {
        const float4* xf = (const float4*)xin_v;
        for (int it = 0; it < 4; ++it) {
            int idx = it * 256 + t;          // 0..1023
            int r = idx >> 4, u8 = idx & 15;
            long fi = (long)(base + r) * 32 + u8 * 2;
            float4 v0 = xf[fi], v1 = xf[fi + 1];
            uint4 wv;
            wv.x = (unsigned)f2b(v0.x) | ((unsigned)f2b(v0.y) << 16);
            wv.y = (unsigned)f2b(v0.z) | ((unsigned)f2b(v0.w) << 16);
            wv.z = (unsigned)f2b(v1.x) | ((unsigned)f2b(v1.y) << 16);
            wv.w = (unsigned)f2b(v1.z) | ((unsigned)f2b(v1.w) << 16);
            *(uint4*)&sX[r * LSTR + u8 * 8] = wv;
        }
    } else {
        const uint4* xb = (const uint4*)xin_v;
        for (int it = 0; it < 4; ++it) {
            int idx = it * 256 + t;
            int r = idx >> 4, u8 = idx & 15;
            *(uint4*)&sX[r * LSTR + u8 * 8] = xb[(long)(base + r) * 16 + u8];
        }
    }

    // ---- mean aggregation: gather neighbor rows from L2, write bf16 mean -> sM
    int lane = t & 63, wid = t >> 6;
    int sub = lane >> 4, fl = lane & 15;      // 4 nodes concurrent/wave; lane owns feats fl*8..+7
    for (int bt = 0; bt < 4; ++bt) {
        int r = wid * 16 + bt * 4 + sub;
        long o = base + r;
        float acc[8] = {0, 0, 0, 0, 0, 0, 0, 0};
        if (alive[o] != 0.0f) {
            int n = cnt[o]; if (n > CAP) n = CAP;
            const int* cp = &col[o * (long)CAP];
            if (XF32) {
                const float4* xf = (const float4*)xin_v;
                int i = 0;
                for (; i + 4 <= n; i += 4) {
                    long r0 = (long)cp[i] * 32 + fl * 2;
                    long r1 = (long)cp[i + 1] * 32 + fl * 2;
                    long r2 = (long)cp[i + 2] * 32 + fl * 2;
                    long r3 = (long)cp[i + 3] * 32 + fl * 2;
                    float4 a0 = xf[r0], c0 = xf[r0 + 1];
                    float4 a1 = xf[r1], c1 = xf[r1 + 1];
                    float4 a2 = xf[r2], c2 = xf[r2 + 1];
                    float4 a3 = xf[r3], c3 = xf[r3 + 1];
                    accf(acc, a0, c0); accf(acc, a1, c1);
                    accf(acc, a2, c2); accf(acc, a3, c3);
                }
                for (; i < n; ++i) {
                    long r0 = (long)cp[i] * 32 + fl * 2;
                    float4 a0 = xf[r0], c0 = xf[r0 + 1];
                    accf(acc, a0, c0);
                }
            } else {
                const uint4* xb = (const uint4*)xin_v;
                int i = 0;
                for (; i + 8 <= n; i += 8) {
                    uint4 u0 = xb[(long)cp[i] * 16 + fl];
                    uint4 u1 = xb[(long)cp[i + 1] * 16 + fl];
                    uint4 u2 = xb[(long)cp[i + 2] * 16 + fl];
                    uint4 u3 = xb[(long)cp[i + 3] * 16 + fl];
                    uint4 u4 = xb[(long)cp[i + 4] * 16 + fl];
                    uint4 u5 = xb[(long)cp[i + 5] * 16 + fl];
                    uint4 u6 = xb[(long)cp[i + 6] * 16 + fl];
                    uint4 u7 = xb[(long)cp[i + 7] * 16 + fl];
                    acc8(acc, u0); acc8(acc, u1); acc8(acc, u2); acc8(acc, u3);
                    acc8(acc, u4); acc8(acc, u5); acc8(acc, u6); acc8(acc, u7);
                }
                for (; i + 2 <= n; i += 2) {
                    uint4 u0 = xb[(long)cp[i] * 16 + fl];
                    uint4 u1 = xb[(long)cp[i + 1] * 16 + fl];
                    acc8(acc, u0); acc8(acc, u1);
                }
                if (i < n) {
                    uint4 u0 = xb[(long)cp[i] * 16 + fl];
                    acc8(acc, u0);
                }
            }
            float rl = rliv[o];
#pragma unroll
            for (int k2 = 0; k2 < 8; ++k2) acc[k2] *= rl;
        }
        *(uint4*)&sM[r * LSTR + fl * 8] = pack8(acc);   // dead rows -> zeros
    }

    // ---- preload stage-0 B fragments (Wr^T, L2-hot), init acc with bias
    int quad = lane >> 4, l15 = lane & 15;
    int wrow0 = (wid & 1) * 32, wcol0 = (wid >> 1) * 64;
    short8 Bf[4][4];
#pragma unroll
    for (int ct = 0; ct < 4; ++ct)
#pragma unroll
        for (int ks = 0; ks < 4; ++ks)
            Bf[ct][ks] = *(const short8*)&wr_bt[(wcol0 + ct * 16 + l15) * HD + ks * 32 + quad * 8];
    floatx4 acc[2][4];
#pragma unroll
    for (int ct = 0; ct < 4; ++ct) {
        float bv = bias[wcol0 + ct * 16 + l15];
#pragma unroll
        for (int nt = 0; nt < 2; ++nt) { acc[nt][ct][0] = bv; acc[nt][ct][1] = bv; acc[nt][ct][2] = bv; acc[nt][ct][3] = bv; }
    }
    __syncthreads();

    // ---- stage 0: mean @ Wr
#pragma unroll
    for (int ks = 0; ks < 4; ++ks) {
        short8 Af[2];
#pragma unroll
        for (int nt = 0; nt < 2; ++nt)
            Af[nt] = *(const short8*)&sM[(wrow0 + nt * 16 + l15) * LSTR + ks * 32 + quad * 8];
#pragma unroll
        for (int ct = 0; ct < 4; ++ct)
#pragma unroll
            for (int nt = 0; nt < 2; ++nt)
                acc[nt][ct] = __builtin_amdgcn_mfma_f32_16x16x32_bf16(Af[nt], Bf[ct][ks], acc[nt][ct], 0, 0, 0);
    }
    // ---- reload B (Ws^T), stage 1: x @ Ws
#pragma unroll
    for (int ct = 0; ct < 4; ++ct)
#pragma unroll
        for (int ks = 0; ks < 4; ++ks)
            Bf[ct][ks] = *(const short8*)&ws_bt[(wcol0 + ct * 16 + l15) * HD + ks * 32 + quad * 8];
#pragma unroll
    for (int ks = 0; ks < 4; ++ks) {
        short8 Af[2];
#pragma unroll
        for (int nt = 0; nt < 2; ++nt)
            Af[nt] = *(const short8*)&sX[(wrow0 + nt * 16 + l15) * LSTR + ks * 32 + quad * 8];
#pragma unroll
        for (int ct = 0; ct < 4; ++ct)
#pragma unroll
            for (int nt = 0; nt < 2; ++nt)
                acc[nt][ct] = __builtin_amdgcn_mfma_f32_16x16x32_bf16(Af[nt], Bf[ct][ks], acc[nt][ct], 0, 0, 0);
    }

    // ---- epilogue: relu, alive-gate (dead rows -> 0), bf16 store, per-graph readout
    int g0 = base / NPG0;
    int cut = (g0 + 1) * NPG0 - base;     // rows >= cut belong to graph g0+1
    bool hasB = cut < TR;
#pragma unroll
    for (int ct = 0; ct < 4; ++ct) {
        int j = wcol0 + ct * 16 + l15;
        float ps0 = 0.0f, ps1 = 0.0f;
#pragma unroll
        for (int nt = 0; nt < 2; ++nt) {
#pragma unroll
            for (int rr = 0; rr < 4; ++rr) {
                int row = wrow0 + nt * 16 + quad * 4 + rr;
                float v = fmaxf(acc[nt][ct][rr], 0.0f);
                bool liv = sAl[row] != 0.0f;
                float sv = liv ? v : 0.0f;
                xout[(long)(base + row) * HD + j] = f2b(sv);
                if (liv) { if (row < cut) ps0 += v; else ps1 += v; }
            }
        }
        ps0 += __shfl_xor(ps0, 16); ps0 += __shfl_xor(ps0, 32);
        if (hasB) { ps1 += __shfl_xor(ps1, 16); ps1 += __shfl_xor(ps1, 32); }
        if (quad == 0) {
            atomicAdd(&hcat[g0 * (5 * HD) + layer * HD + j], ps0);
            if (hasB) atomicAdd(&hcat[(g0 + 1) * (5 * HD) + layer * HD + j], ps1);
        }
    }
}

// ---------------- fused pool: dots + score + top-K + tanh-scale + rliv update
// one block per graph. score = mean_j(x_j.wr) + x.ws + b  (mean commutes with H->1 proj)
__global__ __launch_bounds__(256) void k_pool(unsigned short* __restrict__ x,
    float* __restrict__ alive, float* __restrict__ rliv,
    const int* __restrict__ cnt, const int* __restrict__ col,
    const float* __restrict__ wr, const float* __restrict__ ws,
    const float* __restrict__ pb, int K)
{
    __shared__ float str[NPG0];
    __shared__ float stsb[NPG0];
    __shared__ float sal[NPG0];
    __shared__ float s[512];
    __shared__ float sc[NPG0];
    __shared__ float mult[NPG0];
    __shared__ unsigned char keep[NPG0];
    __shared__ int cnt_gt;
    int g = blockIdx.x, t = threadIdx.x;
    long nb = (long)g * NPG0;

    // phase 1: per-node dots tr = x.wr, tsb = x.ws + b  (8 nodes concurrent, 32 lanes each)
    int lane32 = t & 31, y = t >> 5;
    float4 w1 = ((const float4*)wr)[lane32];
    float4 w2 = ((const float4*)ws)[lane32];
    float pbv = pb[0];
    for (int b = 0; b < 50; ++b) {
        int n = b * 8 + y;
        uint2 u = ((const uint2*)x)[(nb + n) * 32 + lane32];
        float x0 = b2f_lo(u.x), x1 = b2f_hi(u.x), x2 = b2f_lo(u.y), x3 = b2f_hi(u.y);
        float a = x0 * w1.x + x1 * w1.y + x2 * w1.z + x3 * w1.w;
        float c = x0 * w2.x + x1 * w2.y + x2 * w2.z + x3 * w2.w;
#pragma unroll
        for (int m = 1; m < 32; m <<= 1) { a += __shfl_xor(a, m); c += __shfl_xor(c, m); }
        if (lane32 == 0) { str[n] = a; stsb[n] = c + pbv; }
    }
    for (int n = t; n < NPG0; n += 256) sal[n] = alive[nb + n];
    if (t == 0) cnt_gt = 0;
    __syncthreads();

    // phase 2: score via LDS gather of tr
    for (int n = t; n < 512; n += 256) {
        float v = -INFINITY;
        if (n < NPG0 && sal[n] != 0.0f) {
            long o = nb + n;
            int m = cnt[o]; if (m > CAP) m = CAP;
            const int* cp = &col[o * (long)CAP];
            float ssum = 0.0f;
            for (int i = 0; i < m; i++) ssum += str[cp[i] - (int)nb];
            v = ssum * rliv[o] + stsb[n];
        }
        s[n] = v;
        if (n < NPG0) sc[n] = v;
    }
    __syncthreads();

    // phase 3: bitonic sort (512) for the K-th largest threshold
    for (int ksz = 2; ksz <= 512; ksz <<= 1) {
        for (int jsz = ksz >> 1; jsz >= 1; jsz >>= 1) {
            for (int i = t; i < 512; i += 256) {
                int ixj = i ^ jsz;
                if (ixj > i) {
                    float a = s[i], c = s[ixj];
                    bool up = ((i & ksz) == 0);
                    if ((a > c) == up) { s[i] = c; s[ixj] = a; }
                }
            }
            __syncthreads();
        }
    }
    float thr = s[512 - K];
    for (int n = t; n < NPG0; n += 256)
        if (sc[n] > thr) atomicAdd(&cnt_gt, 1);
    __syncthreads();
    if (t == 0) {   // tie-break: lowest index (matches lax.top_k)
        int m = K - cnt_gt, tk = 0;
        for (int n = 0; n < NPG0; n++) {
            bool kp = sc[n] > thr;
            if (!kp && sc[n] == thr && tk < m) { kp = true; tk++; }
            keep[n] = kp ? 1 : 0;
        }
    }
    __syncthreads();
    for (int n = t; n < NPG0; n += 256) {
        mult[n] = keep[n] ? tanhf(sc[n]) : 0.0f;
        alive[nb + n] = keep[n] ? 1.0f : 0.0f;
    }
    __syncthreads();
    // rliv update from keep mask (edges are intra-graph)
    for (int n = t; n < NPG0; n += 256) {
        long o = nb + n;
        int m = cnt[o]; if (m > CAP) m = CAP;
        const int* cp = &col[o * (long)CAP];
        float ssum = 0.0f;
        for (int i = 0; i < m; i++) ssum += keep[cp[i] - (int)nb] ? 1.0f : 0.0f;
        rliv[o] = 1.0f / fmaxf(ssum, 1.0f);
    }
    // x *= mult (tanh scale kept, zero dropped)
    for (int idx = t; idx < NPG0 * 32; idx += 256) {
        int n = idx >> 5, c4 = idx & 31;
        uint2* p = (uint2*)&x[(nb + n) * HD + c4 * 4];
        uint2 u = *p;
        float m = mult[n];
        uint2 w;
        w.x = (unsigned)f2b(b2f_lo(u.x) * m) | ((unsigned)f2b(b2f_hi(u.x) * m) << 16);
        w.y = (unsigned)f2b(b2f_lo(u.y) * m) | ((unsigned)f2b(b2f_hi(u.y) * m) << 16);
        *p = w;
    }
}

// ---------------- final MLP + log_softmax (hcat holds SUMS; divide by npg here)
__global__ __launch_bounds__(128) void k_mlp(const float* __restrict__ h, const float* __restrict__ w1,
    const float* __restrict__ b1, const float* __restrict__ w2,
    const float* __restrict__ b2, float* __restrict__ out) {
    __shared__ float h1[HD];
    __shared__ float red[HD];
    __shared__ float lg[2];
    const float inv[5] = {1.0f/400.0f, 1.0f/400.0f, 1.0f/320.0f, 1.0f/320.0f, 1.0f/256.0f};
    int g = blockIdx.x, j = threadIdx.x;
    const float* hg = &h[g * (5 * HD)];
    float acc = b1[j];
    for (int k = 0; k < 5 * HD; k++) acc += hg[k] * inv[k >> 7] * w1[k * HD + j];
    h1[j] = fmaxf(acc, 0.0f);
    __syncthreads();
    for (int c = 0; c < 2; c++) {
        red[j] = h1[j] * w2[j * 2 + c];
        __syncthreads();
        for (int st = 64; st > 0; st >>= 1) {
            if (j < st) red[j] += red[j + st];
            __syncthreads();
        }
        if (j == 0) lg[c] = red[0] + b2[c];
        __syncthreads();
    }
    if (j == 0) {
        float l0 = lg[0], l1 = lg[1];
        float m = fmaxf(l0, l1);
        float lse = m + logf(expf(l0 - m) + expf(l1 - m));
        out[g * 2 + 0] = l0 - lse;
        out[g * 2 + 1] = l1 - lse;
    }
}

extern "C" void kernel_launch(void* const* d_in, const int* in_sizes, int n_in,
                              void* d_out, int out_size, void* d_ws, size_t ws_size,
                              hipStream_t stream) {
    const float* x_in   = (const float*)d_in[0];
    const int*   eidx   = (const int*)d_in[1];
    const int*   e_src  = eidx;
    const int*   e_dst  = eidx + NE;
    const float* c1_wr  = (const float*)d_in[3];
    const float* c1_ws  = (const float*)d_in[4];
    const float* c1_b   = (const float*)d_in[5];
    const float* cs_wr  = (const float*)d_in[6];
    const float* cs_ws  = (const float*)d_in[7];
    const float* cs_b   = (const float*)d_in[8];
    const float* p_wr   = (const float*)d_in[9];
    const float* p_ws   = (const float*)d_in[10];
    const float* p_b    = (const float*)d_in[11];
    const float* l1_w   = (const float*)d_in[12];
    const float* l1_b   = (const float*)d_in[13];
    const float* l2_w   = (const float*)d_in[14];
    const float* l2_b   = (const float*)d_in[15];
    float* out = (float*)d_out;

    char* ws = (char*)d_ws;
    size_t off = 0;
    int*   cnt   = (int*)(ws + off);             off += (size_t)NN * 4;
    int*   col   = (int*)(ws + off);             off += (size_t)NN * CAP * 4;
    float* alive = (float*)(ws + off);           off += (size_t)NN * 4;
    float* rliv  = (float*)(ws + off);           off += (size_t)NN * 4;
    unsigned short* xb0 = (unsigned short*)(ws + off); off += (size_t)NN * HD * 2;
    unsigned short* xb1 = (unsigned short*)(ws + off); off += (size_t)NN * HD * 2;
    float* hcat  = (float*)(ws + off);           off += (size_t)BGR * 5 * HD * 4;
    unsigned short* wbt = (unsigned short*)(ws + off); off += (size_t)10 * HD * HD * 2;

    hipMemsetAsync(cnt, 0, (size_t)NN * 4, stream);
    hipMemsetAsync(hcat, 0, (size_t)BGR * 5 * HD * 4, stream);
    k_build<<<(NE + 255) / 256, 256, 0, stream>>>(e_src, e_dst, cnt, col);
    k_initrl<<<NN / 256, 256, 0, stream>>>(cnt, alive, rliv);
    k_wcvt<<<dim3(64, 10), 256, 0, stream>>>(c1_wr, c1_ws, cs_wr, cs_ws, wbt);

    unsigned short* bt_wr[5] = { wbt + 0 * HD * HD, wbt + 2 * HD * HD, wbt + 3 * HD * HD, wbt + 4 * HD * HD, wbt + 5 * HD * HD };
    unsigned short* bt_ws[5] = { wbt + 1 * HD * HD, wbt + 6 * HD * HD, wbt + 7 * HD * HD, wbt + 8 * HD * HD, wbt + 9 * HD * HD };

    // conv1: x_in(fp32) -> xb0
    k_layer<true><<<NN / TR, 256, 0, stream>>>(x_in, xb0, cnt, col, alive, rliv,
                                               bt_wr[0], bt_ws[0], c1_b, hcat, 0);
    // convs[0]: xb0 -> xb1
    k_layer<false><<<NN / TR, 256, 0, stream>>>(xb0, xb1, cnt, col, alive, rliv,
                                                bt_wr[1], bt_ws[1], cs_b + 0 * HD, hcat, 1);
    // pool 0 (K=320) on xb1
    k_pool<<<BGR, 256, 0, stream>>>(xb1, alive, rliv, cnt, col,
                                    p_wr + 0 * HD, p_ws + 0 * HD, p_b + 0, 320);
    // convs[1]: xb1 -> xb0
    k_layer<false><<<NN / TR, 256, 0, stream>>>(xb1, xb0, cnt, col, alive, rliv,
                                                bt_wr[2], bt_ws[2], cs_b + 1 * HD, hcat, 2);
    // convs[2]: xb0 -> xb1
    k_layer<false><<<NN / TR, 256, 0, stream>>>(xb0, xb1, cnt, col, alive, rliv,
                                                bt_wr[3], bt_ws[3], cs_b + 2 * HD, hcat, 3);
    // pool 1 (K=256) on xb1
    k_pool<<<BGR, 256, 0, stream>>>(xb1, alive, rliv, cnt, col,
                                    p_wr + 1 * HD, p_ws + 1 * HD, p_b + 1, 256);
    // convs[3]: xb1 -> xb0
    k_layer<false><<<NN / TR, 256, 0, stream>>>(xb1, xb0, cnt, col, alive, rliv,
                                                bt_wr[4], bt_ws[4], cs_b + 3 * HD, hcat, 4);
    // MLP head
    k_mlp<<<BGR, HD, 0, stream>>>(hcat, l1_w, l1_b, l2_w, l2_b, out);
}

// Round 6
// 722.007 us; speedup vs baseline: 1.1402x; 1.0315x over previous
//
#include <hip/hip_runtime.h>
#include <math.h>

#define BGR 256        // graphs
#define NPG0 400       // nodes per graph
#define NN (BGR*NPG0)  // 102400 nodes
#define NE (NN*16)     // 1638400 edges
#define HD 128
#define CAP 64         // CSR capacity (pools only)
#define AST 416        // dense adjacency row stride (bytes), K padded to 13*32
#define KSA 13         // agg k-steps (13*32 = 416)
#define XSTR 424       // XT LDS row stride (shorts), 16B-aligned
#define MSTR 136       // mean LDS row stride (shorts), 16B-aligned
#define SUSZ 54400     // union LDS shorts: max(128*424=54272, 400*136=54400)

typedef __attribute__((ext_vector_type(8))) short short8;
typedef __attribute__((ext_vector_type(4))) float floatx4;

__device__ __forceinline__ unsigned short f2b(float f) {
    unsigned int u = __builtin_bit_cast(unsigned int, f);
    unsigned int r = (u + 0x7fffu + ((u >> 16) & 1u)) >> 16;
    return (unsigned short)r;
}
__device__ __forceinline__ unsigned int pk2(float a, float b) {
    return (unsigned int)f2b(a) | ((unsigned int)f2b(b) << 16);
}
__device__ __forceinline__ float b2f_lo(unsigned int u) { return __builtin_bit_cast(float, u << 16); }
__device__ __forceinline__ float b2f_hi(unsigned int u) { return __builtin_bit_cast(float, u & 0xffff0000u); }
__device__ __forceinline__ short bfint(unsigned int v) {
    // exact bf16 of small nonneg int (v < 256)
    return (short)(__builtin_bit_cast(unsigned int, (float)v) >> 16);
}
__device__ __forceinline__ short8 ub8_bf16(uint2 u) {
    short8 r;
    r[0] = bfint(u.x & 0xffu);        r[1] = bfint((u.x >> 8) & 0xffu);
    r[2] = bfint((u.x >> 16) & 0xffu); r[3] = bfint(u.x >> 24);
    r[4] = bfint(u.y & 0xffu);        r[5] = bfint((u.y >> 8) & 0xffu);
    r[6] = bfint((u.y >> 16) & 0xffu); r[7] = bfint(u.y >> 24);
    return r;
}

// ---------------- CSR build (pools only) ----------------
__global__ void k_build(const int* __restrict__ src, const int* __restrict__ dst,
                        int* __restrict__ cnt, int* __restrict__ col) {
    int e = blockIdx.x * 256 + threadIdx.x;
    if (e >= NE) return;
    int d = dst[e], s = src[e];
    int i = atomicAdd(&cnt[d], 1);
    if (i < CAP) col[d * CAP + i] = s;
}

// ---------------- dense adjacency build: A_u8[g][dst_local][src_local] += 1 (packed atomics)
__global__ void k_abuild(const int* __restrict__ src, const int* __restrict__ dst,
                         unsigned int* __restrict__ A) {
    int e = blockIdx.x * 256 + threadIdx.x;
    if (e >= NE) return;
    int s = src[e], d = dst[e];
    int g = d / NPG0;
    long idx = ((long)g * NPG0 + (d - g * NPG0)) * AST + (s - g * NPG0);   // byte index
    atomicAdd(&A[idx >> 2], 1u << ((idx & 3) * 8));
}

// alive=1, rliv = 1/max(deg,1) (exact degree incl. multi-edges)
__global__ void k_initrl(const int* __restrict__ cnt, float* __restrict__ alive,
                         float* __restrict__ rliv) {
    int i = blockIdx.x * 256 + threadIdx.x;
    if (i >= NN) return;
    alive[i] = 1.0f;
    rliv[i] = 1.0f / fmaxf((float)cnt[i], 1.0f);
}

// ---------------- W -> bf16, transposed: bt[m][j*128 + f] = bf16(W_m[f*128 + j]) = W^T row-major
__global__ void k_wcvt(const float* __restrict__ c1_wr, const float* __restrict__ c1_ws,
                       const float* __restrict__ cs_wr, const float* __restrict__ cs_ws,
                       unsigned short* __restrict__ bt) {
    int m = blockIdx.y;
    int idx = blockIdx.x * 256 + threadIdx.x;
    const float* W = (m == 0) ? c1_wr : (m == 1) ? c1_ws
                   : (m < 6) ? (cs_wr + (m - 2) * HD * HD) : (cs_ws + (m - 6) * HD * HD);
    int n = idx >> 7, k = idx & 127;
    bt[m * HD * HD + idx] = f2b(W[k * HD + n]);
}

// ---------------- fused layer (one block per graph, 512 threads):
//  phase1: stage XT[f][s] in LDS (4x4 shfl-transpose, b64 writes)
//  phase2: preload agg A-frags (XT) into regs
//  phase3: meanT = XT . A^T  (B from global u8 adjacency) -> write mean normal-layout
//          into the SAME LDS region (all XT reads done), scaled by rliv
//  phase4: OUT^T = WrT.meanT + WsT.xT + b  (W^T = A-op regs, mean LDS / x global = B-ops)
//          epilogue: relu, alive-gate, store x normal layout, fused per-graph readout
template<bool XF32>
__global__ __launch_bounds__(512, 2) void k_layer2(
    const void* __restrict__ xin_v, unsigned short* __restrict__ xout,
    const unsigned char* __restrict__ Amat,
    const float* __restrict__ alive, const float* __restrict__ rliv,
    const unsigned short* __restrict__ wr_bt, const unsigned short* __restrict__ ws_bt,
    const float* __restrict__ bias, float* __restrict__ hcat, int layer)
{
    __shared__ __align__(16) unsigned short sU[SUSZ];
    int g = blockIdx.x;
    int t = threadIdx.x;
    long gbase = (long)g * NPG0;

    // ---- phase 1: stage XT
    for (int it = 0; it < 25; ++it) {
        int task = it * 128 + (t >> 2);
        int j = t & 3;
        int r0 = (task >> 5) * 4;
        int f0 = (task & 31) * 4;
        float a0, a1, a2, a3;
        if (XF32) {
            float4 v = ((const float4*)xin_v)[(gbase + r0 + j) * 32 + (f0 >> 2)];
            a0 = v.x; a1 = v.y; a2 = v.z; a3 = v.w;
        } else {
            uint2 u = ((const uint2*)xin_v)[(gbase + r0 + j) * 32 + (f0 >> 2)];
            a0 = b2f_lo(u.x); a1 = b2f_hi(u.x); a2 = b2f_lo(u.y); a3 = b2f_hi(u.y);
        }
        float tw;
        bool bo1 = j & 1;
        tw = __shfl_xor(bo1 ? a0 : a1, 1); if (bo1) a0 = tw; else a1 = tw;
        tw = __shfl_xor(bo1 ? a2 : a3, 1); if (bo1) a2 = tw; else a3 = tw;
        bool bo2 = (j & 2) != 0;
        tw = __shfl_xor(bo2 ? a0 : a2, 2); if (bo2) a0 = tw; else a2 = tw;
        tw = __shfl_xor(bo2 ? a1 : a3, 2); if (bo2) a1 = tw; else a3 = tw;
        // lane j now holds feat f0+j for nodes r0..r0+3
        uint2 w; w.x = pk2(a0, a1); w.y = pk2(a2, a3);
        *(uint2*)&sU[(f0 + j) * XSTR + r0] = w;
    }
    // zero k-pad columns 400..415
    for (int idx = t; idx < HD * 16; idx += 512) {
        int f = idx >> 4, c = idx & 15;
        sU[f * XSTR + 400 + c] = 0;
    }
    __syncthreads();

    int lane = t & 63, wid = t >> 6;      // 8 waves
    int quad = lane >> 4, l15 = lane & 15;
    int mp = wid & 3;                      // feature pair-group: m-tiles 2mp, 2mp+1
    int nh = wid >> 2;                     // node half
    int ntB = nh ? 13 : 0;
    int ntE = nh ? 25 : 13;

    // ---- phase 2: preload agg A-frags (the only XT readers)
    short8 Afr[2][KSA];
#pragma unroll
    for (int mt = 0; mt < 2; ++mt)
#pragma unroll
        for (int k = 0; k < KSA; ++k)
            Afr[mt][k] = *(const short8*)&sU[((2 * mp + mt) * 16 + l15) * XSTR + k * 32 + quad * 8];

    // prefetch first adjacency B-rows (global; safe before barrier)
    const unsigned char* Ag = Amat + gbase * AST;
    uint2 bw[KSA];
    {
        const unsigned char* Ar = Ag + (long)(ntB * 16 + l15) * AST;
#pragma unroll
        for (int k = 0; k < KSA; ++k)
            bw[k] = *(const uint2*)&Ar[k * 32 + quad * 8];
    }
    __syncthreads();   // all XT reads complete; sU may now be overwritten by mean

    // ---- phase 3: agg GEMM + mean write (normal layout, stride MSTR)
    for (int nt = ntB; nt < ntE; ++nt) {
        uint2 cur[KSA];
#pragma unroll
        for (int k = 0; k < KSA; ++k) cur[k] = bw[k];
        if (nt + 1 < ntE) {
            const unsigned char* Ar = Ag + (long)((nt + 1) * 16 + l15) * AST;
#pragma unroll
            for (int k = 0; k < KSA; ++k)
                bw[k] = *(const uint2*)&Ar[k * 32 + quad * 8];
        }
        floatx4 acc0 = {0.f, 0.f, 0.f, 0.f};
        floatx4 acc1 = {0.f, 0.f, 0.f, 0.f};
#pragma unroll
        for (int k = 0; k < KSA; ++k) {
            short8 Bf = ub8_bf16(cur[k]);
            acc0 = __builtin_amdgcn_mfma_f32_16x16x32_bf16(Afr[0][k], Bf, acc0, 0, 0, 0);
            acc1 = __builtin_amdgcn_mfma_f32_16x16x32_bf16(Afr[1][k], Bf, acc1, 0, 0, 0);
        }
        int o = nt * 16 + l15;                 // lane's column = out-node
        float rl = rliv[gbase + o];
        unsigned short* mrow = &sU[o * MSTR + 32 * mp + quad * 4];
        uint2 w0, w1;
        w0.x = pk2(acc0[0] * rl, acc0[1] * rl); w0.y = pk2(acc0[2] * rl, acc0[3] * rl);
        w1.x = pk2(acc1[0] * rl, acc1[1] * rl); w1.y = pk2(acc1[2] * rl, acc1[3] * rl);
        *(uint2*)mrow = w0;
        *(uint2*)(mrow + 16) = w1;
    }
    __syncthreads();

    // ---- phase 4: transposed conv
    short8 Wr8[2][4], Ws8[2][4];
#pragma unroll
    for (int mt = 0; mt < 2; ++mt) {
        int j = (2 * mp + mt) * 16 + l15;
#pragma unroll
        for (int k = 0; k < 4; ++k) {
            Wr8[mt][k] = *(const short8*)&wr_bt[j * HD + k * 32 + quad * 8];
            Ws8[mt][k] = *(const short8*)&ws_bt[j * HD + k * 32 + quad * 8];
        }
    }
    float4 b40 = *(const float4*)&bias[(2 * mp) * 16 + quad * 4];
    float4 b41 = *(const float4*)&bias[(2 * mp + 1) * 16 + quad * 4];
    float ps0[4] = {0, 0, 0, 0}, ps1[4] = {0, 0, 0, 0};

    for (int nt = ntB; nt < ntE; ++nt) {
        int o = nt * 16 + l15;
        long go = gbase + o;
        floatx4 a0 = {b40.x, b40.y, b40.z, b40.w};
        floatx4 a1 = {b41.x, b41.y, b41.z, b41.w};
#pragma unroll
        for (int k = 0; k < 4; ++k) {
            short8 B0 = *(const short8*)&sU[o * MSTR + k * 32 + quad * 8];
            a0 = __builtin_amdgcn_mfma_f32_16x16x32_bf16(Wr8[0][k], B0, a0, 0, 0, 0);
            a1 = __builtin_amdgcn_mfma_f32_16x16x32_bf16(Wr8[1][k], B0, a1, 0, 0, 0);
        }
        if (XF32) {
            const float4* xf = (const float4*)xin_v;
#pragma unroll
            for (int k = 0; k < 4; ++k) {
                float4 v0 = xf[go * 32 + k * 8 + quad * 2];
                float4 v1 = xf[go * 32 + k * 8 + quad * 2 + 1];
                short8 B1;
                B1[0] = (short)f2b(v0.x); B1[1] = (short)f2b(v0.y);
                B1[2] = (short)f2b(v0.z); B1[3] = (short)f2b(v0.w);
                B1[4] = (short)f2b(v1.x); B1[5] = (short)f2b(v1.y);
                B1[6] = (short)f2b(v1.z); B1[7] = (short)f2b(v1.w);
                a0 = __builtin_amdgcn_mfma_f32_16x16x32_bf16(Ws8[0][k], B1, a0, 0, 0, 0);
                a1 = __builtin_amdgcn_mfma_f32_16x16x32_bf16(Ws8[1][k], B1, a1, 0, 0, 0);
            }
        } else {
            const unsigned short* x16 = (const unsigned short*)xin_v;
#pragma unroll
            for (int k = 0; k < 4; ++k) {
                short8 B1 = *(const short8*)&x16[go * HD + k * 32 + quad * 8];
                a0 = __builtin_amdgcn_mfma_f32_16x16x32_bf16(Ws8[0][k], B1, a0, 0, 0, 0);
                a1 = __builtin_amdgcn_mfma_f32_16x16x32_bf16(Ws8[1][k], B1, a1, 0, 0, 0);
            }
        }
        bool liv = alive[go] != 0.0f;
        float v0r[4], v1r[4];
#pragma unroll
        for (int rr = 0; rr < 4; ++rr) {
            v0r[rr] = fmaxf(a0[rr], 0.0f);
            v1r[rr] = fmaxf(a1[rr], 0.0f);
            if (liv) { ps0[rr] += v0r[rr]; ps1[rr] += v1r[rr]; }
            if (!liv) { v0r[rr] = 0.0f; v1r[rr] = 0.0f; }
        }
        unsigned short* orow = &xout[go * HD];
        uint2 w0, w1;
        w0.x = pk2(v0r[0], v0r[1]); w0.y = pk2(v0r[2], v0r[3]);
        w1.x = pk2(v1r[0], v1r[1]); w1.y = pk2(v1r[2], v1r[3]);
        *(uint2*)&orow[(2 * mp) * 16 + quad * 4] = w0;
        *(uint2*)&orow[(2 * mp + 1) * 16 + quad * 4] = w1;
    }
    // fused readout: reduce over l15 (node lanes), atomic into hcat
#pragma unroll
    for (int rr = 0; rr < 4; ++rr) {
        float v = ps0[rr];
        v += __shfl_xor(v, 1); v += __shfl_xor(v, 2); v += __shfl_xor(v, 4); v += __shfl_xor(v, 8);
        float u = ps1[rr];
        u += __shfl_xor(u, 1); u += __shfl_xor(u, 2); u += __shfl_xor(u, 4); u += __shfl_xor(u, 8);
        if (l15 == 0) {
            atomicAdd(&hcat[g * (5 * HD) + layer * HD + (2 * mp) * 16 + quad * 4 + rr], v);
            atomicAdd(&hcat[g * (5 * HD) + layer * HD + (2 * mp + 1) * 16 + quad * 4 + rr], u);
        }
    }
}

// ---------------- fused pool (unchanged from R5): dots + score + top-K + tanh-scale + rliv
__global__ __launch_bounds__(256) void k_pool(unsigned short* __restrict__ x,
    float* __restrict__ alive, float* __restrict__ rliv,
    const int* __restrict__ cnt, const int* __restrict__ col,
    const float* __restrict__ wr, const float* __restrict__ ws,
    const float* __restrict__ pb, int K)
{
    __shared__ float str[NPG0];
    __shared__ float stsb[NPG0];
    __shared__ float sal[NPG0];
    __shared__ float s[512];
    __shared__ float sc[NPG0];
    __shared__ float mult[NPG0];
    __shared__ unsigned char keep[NPG0];
    __shared__ int cnt_gt;
    int g = blockIdx.x, t = threadIdx.x;
    long nb = (long)g * NPG0;

    int lane32 = t & 31, y = t >> 5;
    float4 w1 = ((const float4*)wr)[lane32];
    float4 w2 = ((const float4*)ws)[lane32];
    float pbv = pb[0];
    for (int b = 0; b < 50; ++b) {
        int n = b * 8 + y;
        uint2 u = ((const uint2*)x)[(nb + n) * 32 + lane32];
        float x0 = b2f_lo(u.x), x1 = b2f_hi(u.x), x2 = b2f_lo(u.y), x3 = b2f_hi(u.y);
        float a = x0 * w1.x + x1 * w1.y + x2 * w1.z + x3 * w1.w;
        float c = x0 * w2.x + x1 * w2.y + x2 * w2.z + x3 * w2.w;
#pragma unroll
        for (int m = 1; m < 32; m <<= 1) { a += __shfl_xor(a, m); c += __shfl_xor(c, m); }
        if (lane32 == 0) { str[n] = a; stsb[n] = c + pbv; }
    }
    for (int n = t; n < NPG0; n += 256) sal[n] = alive[nb + n];
    if (t == 0) cnt_gt = 0;
    __syncthreads();

    for (int n = t; n < 512; n += 256) {
        float v = -INFINITY;
        if (n < NPG0 && sal[n] != 0.0f) {
            long o = nb + n;
            int m = cnt[o]; if (m > CAP) m = CAP;
            const int* cp = &col[o * (long)CAP];
            float ssum = 0.0f;
            for (int i = 0; i < m; i++) ssum += str[cp[i] - (int)nb];
            v = ssum * rliv[o] + stsb[n];
        }
        s[n] = v;
        if (n < NPG0) sc[n] = v;
    }
    __syncthreads();

    for (int ksz = 2; ksz <= 512; ksz <<= 1) {
        for (int jsz = ksz >> 1; jsz >= 1; jsz >>= 1) {
            for (int i = t; i < 512; i += 256) {
                int ixj = i ^ jsz;
                if (ixj > i) {
                    float a = s[i], c = s[ixj];
                    bool up = ((i & ksz) == 0);
                    if ((a > c) == up) { s[i] = c; s[ixj] = a; }
                }
            }
            __syncthreads();
        }
    }
    float thr = s[512 - K];
    for (int n = t; n < NPG0; n += 256)
        if (sc[n] > thr) atomicAdd(&cnt_gt, 1);
    __syncthreads();
    if (t == 0) {   // tie-break: lowest index (matches lax.top_k)
        int m = K - cnt_gt, tk = 0;
        for (int n = 0; n < NPG0; n++) {
            bool kp = sc[n] > thr;
            if (!kp && sc[n] == thr && tk < m) { kp = true; tk++; }
            keep[n] = kp ? 1 : 0;
        }
    }
    __syncthreads();
    for (int n = t; n < NPG0; n += 256) {
        mult[n] = keep[n] ? tanhf(sc[n]) : 0.0f;
        alive[nb + n] = keep[n] ? 1.0f : 0.0f;
    }
    __syncthreads();
    for (int n = t; n < NPG0; n += 256) {
        long o = nb + n;
        int m = cnt[o]; if (m > CAP) m = CAP;
        const int* cp = &col[o * (long)CAP];
        float ssum = 0.0f;
        for (int i = 0; i < m; i++) ssum += keep[cp[i] - (int)nb] ? 1.0f : 0.0f;
        rliv[o] = 1.0f / fmaxf(ssum, 1.0f);
    }
    for (int idx = t; idx < NPG0 * 32; idx += 256) {
        int n = idx >> 5, c4 = idx & 31;
        uint2* p = (uint2*)&x[(nb + n) * HD + c4 * 4];
        uint2 u = *p;
        float m = mult[n];
        uint2 w;
        w.x = pk2(b2f_lo(u.x) * m, b2f_hi(u.x) * m);
        w.y = pk2(b2f_lo(u.y) * m, b2f_hi(u.y) * m);
        *p = w;
    }
}

// ---------------- final MLP + log_softmax (hcat holds SUMS; divide here)
__global__ __launch_bounds__(128) void k_mlp(const float* __restrict__ h, const float* __restrict__ w1,
    const float* __restrict__ b1, const float* __restrict__ w2,
    const float* __restrict__ b2, float* __restrict__ out) {
    __shared__ float h1[HD];
    __shared__ float red[HD];
    __shared__ float lg[2];
    const float inv[5] = {1.0f/400.0f, 1.0f/400.0f, 1.0f/320.0f, 1.0f/320.0f, 1.0f/256.0f};
    int g = blockIdx.x, j = threadIdx.x;
    const float* hg = &h[g * (5 * HD)];
    float acc = b1[j];
    for (int k = 0; k < 5 * HD; k++) acc += hg[k] * inv[k >> 7] * w1[k * HD + j];
    h1[j] = fmaxf(acc, 0.0f);
    __syncthreads();
    for (int c = 0; c < 2; c++) {
        red[j] = h1[j] * w2[j * 2 + c];
        __syncthreads();
        for (int st = 64; st > 0; st >>= 1) {
            if (j < st) red[j] += red[j + st];
            __syncthreads();
        }
        if (j == 0) lg[c] = red[0] + b2[c];
        __syncthreads();
    }
    if (j == 0) {
        float l0 = lg[0], l1 = lg[1];
        float m = fmaxf(l0, l1);
        float lse = m + logf(expf(l0 - m) + expf(l1 - m));
        out[g * 2 + 0] = l0 - lse;
        out[g * 2 + 1] = l1 - lse;
    }
}

extern "C" void kernel_launch(void* const* d_in, const int* in_sizes, int n_in,
                              void* d_out, int out_size, void* d_ws, size_t ws_size,
                              hipStream_t stream) {
    const float* x_in   = (const float*)d_in[0];
    const int*   eidx   = (const int*)d_in[1];
    const int*   e_src  = eidx;
    const int*   e_dst  = eidx + NE;
    const float* c1_wr  = (const float*)d_in[3];
    const float* c1_ws  = (const float*)d_in[4];
    const float* c1_b   = (const float*)d_in[5];
    const float* cs_wr  = (const float*)d_in[6];
    const float* cs_ws  = (const float*)d_in[7];
    const float* cs_b   = (const float*)d_in[8];
    const float* p_wr   = (const float*)d_in[9];
    const float* p_ws   = (const float*)d_in[10];
    const float* p_b    = (const float*)d_in[11];
    const float* l1_w   = (const float*)d_in[12];
    const float* l1_b   = (const float*)d_in[13];
    const float* l2_w   = (const float*)d_in[14];
    const float* l2_b   = (const float*)d_in[15];
    float* out = (float*)d_out;

    char* ws = (char*)d_ws;
    size_t off = 0;
    int*   cnt   = (int*)(ws + off);             off += (size_t)NN * 4;
    int*   col   = (int*)(ws + off);             off += (size_t)NN * CAP * 4;
    float* alive = (float*)(ws + off);           off += (size_t)NN * 4;
    float* rliv  = (float*)(ws + off);           off += (size_t)NN * 4;
    unsigned short* xb0 = (unsigned short*)(ws + off); off += (size_t)NN * HD * 2;
    unsigned short* xb1 = (unsigned short*)(ws + off); off += (size_t)NN * HD * 2;
    float* hcat  = (float*)(ws + off);           off += (size_t)BGR * 5 * HD * 4;
    unsigned short* wbt = (unsigned short*)(ws + off); off += (size_t)10 * HD * HD * 2;
    unsigned char* Amat = (unsigned char*)(ws + off);  off += (size_t)NN * AST;

    hipMemsetAsync(cnt, 0, (size_t)NN * 4, stream);
    hipMemsetAsync(hcat, 0, (size_t)BGR * 5 * HD * 4, stream);
    hipMemsetAsync(Amat, 0, (size_t)NN * AST, stream);
    k_build<<<(NE + 255) / 256, 256, 0, stream>>>(e_src, e_dst, cnt, col);
    k_abuild<<<(NE + 255) / 256, 256, 0, stream>>>(e_src, e_dst, (unsigned int*)Amat);
    k_initrl<<<NN / 256, 256, 0, stream>>>(cnt, alive, rliv);
    k_wcvt<<<dim3(64, 10), 256, 0, stream>>>(c1_wr, c1_ws, cs_wr, cs_ws, wbt);

    unsigned short* bt_wr[5] = { wbt + 0 * HD * HD, wbt + 2 * HD * HD, wbt + 3 * HD * HD, wbt + 4 * HD * HD, wbt + 5 * HD * HD };
    unsigned short* bt_ws[5] = { wbt + 1 * HD * HD, wbt + 6 * HD * HD, wbt + 7 * HD * HD, wbt + 8 * HD * HD, wbt + 9 * HD * HD };

    // conv1: x_in(fp32) -> xb0
    k_layer2<true><<<BGR, 512, 0, stream>>>(x_in, xb0, Amat, alive, rliv,
                                            bt_wr[0], bt_ws[0], c1_b, hcat, 0);
    // convs[0]: xb0 -> xb1
    k_layer2<false><<<BGR, 512, 0, stream>>>(xb0, xb1, Amat, alive, rliv,
                                             bt_wr[1], bt_ws[1], cs_b + 0 * HD, hcat, 1);
    // pool 0 (K=320) on xb1
    k_pool<<<BGR, 256, 0, stream>>>(xb1, alive, rliv, cnt, col,
                                    p_wr + 0 * HD, p_ws + 0 * HD, p_b + 0, 320);
    // convs[1]: xb1 -> xb0
    k_layer2<false><<<BGR, 512, 0, stream>>>(xb1, xb0, Amat, alive, rliv,
                                             bt_wr[2], bt_ws[2], cs_b + 1 * HD, hcat, 2);
    // convs[2]: xb0 -> xb1
    k_layer2<false><<<BGR, 512, 0, stream>>>(xb0, xb1, Amat, alive, rliv,
                                             bt_wr[3], bt_ws[3], cs_b + 2 * HD, hcat, 3);
    // pool 1 (K=256) on xb1
    k_pool<<<BGR, 256, 0, stream>>>(xb1, alive, rliv, cnt, col,
                                    p_wr + 1 * HD, p_ws + 1 * HD, p_b + 1, 256);
    // convs[3]: xb1 -> xb0
    k_layer2<false><<<BGR, 512, 0, stream>>>(xb1, xb0, Amat, alive, rliv,
                                             bt_wr[4], bt_ws[4], cs_b + 3 * HD, hcat, 4);
    // MLP head
    k_mlp<<<BGR, HD, 0, stream>>>(hcat, l1_w, l1_b, l2_w, l2_b, out);
}